// Round 3
// baseline (108.830 us; speedup 1.0000x reference)
//
#include <hip/hip_runtime.h>
#include <hip/hip_bf16.h>
#include <stdint.h>

// Chamfer loss: dist = ||x||^2 + ||y||^2 - 2 x.y via bf16 hi/lo-split MFMA.
// X pre-scaled by -2 (exact); acc initialized with x^2+y^2 so the accumulator
// IS the distance; epilogue = pure min reductions + device atomicMin.
// Persistent blocks: 256 blocks x 512 thr, each owns 4 tiles (same bi, 4 bj),
// XCD 2D super-tiling (16bi x 8bj per XCD -> 3MB L2 working set).
// Staging pipelines continuously across tiles; finalize fused via last-block.

typedef __bf16  bf16x8 __attribute__((ext_vector_type(8)));
typedef float   f32x4  __attribute__((ext_vector_type(4)));

#define NPTS 8192
#define DIM  128
#define KC   256   // hi (0..127) | lo (128..255)

__device__ __forceinline__ void gload_lds16(const void* gsrc, void* ldst) {
  __builtin_amdgcn_global_load_lds(
      (const __attribute__((address_space(1))) uint32_t*)(uintptr_t)gsrc,
      (__attribute__((address_space(3))) uint32_t*)(uintptr_t)ldst,
      16, 0, 0);
}

// ---------------------------------------------------------------- prep ----
__global__ __launch_bounds__(256) void prep_kernel(
    const float* __restrict__ x, const float* __restrict__ y,
    unsigned short* __restrict__ Xc, unsigned short* __restrict__ Yc,
    float* __restrict__ x2, float* __restrict__ y2,
    unsigned int* __restrict__ minx, unsigned int* __restrict__ miny,
    unsigned int* __restrict__ cnt)
{
  const int gt  = blockIdx.x * 256 + threadIdx.x;   // 0 .. 524287
  const int row = gt >> 5;                          // 0 .. 16383
  const int seg = gt & 31;                          // float4 slot in row
  const bool isx = row < NPTS;
  const float* src        = isx ? (x  + (size_t)row * DIM) : (y  + (size_t)(row - NPTS) * DIM);
  unsigned short* dst     = isx ? (Xc + (size_t)row * KC)  : (Yc + (size_t)(row - NPTS) * KC);

  f32x4 v = *reinterpret_cast<const f32x4*>(src + seg * 4);
  float sq = v[0]*v[0] + v[1]*v[1] + v[2]*v[2] + v[3]*v[3];
  #pragma unroll
  for (int m = 1; m <= 16; m <<= 1) sq += __shfl_xor(sq, m);   // 32-lane segmented reduce
  if (seg == 0) { if (isx) x2[row] = sq; else y2[row - NPTS] = sq; }

  const float scale = isx ? -2.0f : 1.0f;           // fold the -2 into X (exact)
  unsigned short hb[4], lb[4];
  #pragma unroll
  for (int i = 0; i < 4; ++i) {
    float f = scale * v[i];
    __hip_bfloat16 h = __float2bfloat16(f);
    float hf = __bfloat162float(h);
    __hip_bfloat16 l = __float2bfloat16(f - hf);
    hb[i] = __builtin_bit_cast(unsigned short, h);
    lb[i] = __builtin_bit_cast(unsigned short, l);
  }
  *reinterpret_cast<ushort4*>(dst + seg * 4)       = make_ushort4(hb[0], hb[1], hb[2], hb[3]);
  *reinterpret_cast<ushort4*>(dst + 128 + seg * 4) = make_ushort4(lb[0], lb[1], lb[2], lb[3]);

  if (gt < NPTS)          minx[gt]        = 0x7F800000u;   // +inf
  else if (gt < 2 * NPTS) miny[gt - NPTS] = 0x7F800000u;
  if (gt == 0) cnt[0] = 0u;
}

// ---------------------------------------------------------------- gemm ----
__global__ __launch_bounds__(512, 2) void chamfer_gemm(
    const unsigned short* __restrict__ Xc, const unsigned short* __restrict__ Yc,
    const float* __restrict__ x2, const float* __restrict__ y2,
    unsigned int* __restrict__ minx, unsigned int* __restrict__ miny,
    unsigned int* __restrict__ cnt, float* __restrict__ out)
{
  __shared__ alignas(16) unsigned short As[2][256 * 64];   // 32 KB each
  __shared__ alignas(16) unsigned short Bs[2][256 * 64];
  __shared__ float colminLDS[2 * 256];
  __shared__ float rowminLDS[4 * 256];
  __shared__ float redLDS[8];
  __shared__ unsigned int lastFlag;

  const int tid  = threadIdx.x;
  const int lane = tid & 63;
  const int w    = tid >> 6;        // 0..7
  const int wr   = w >> 2;          // 0..1  (rows: wr*128)
  const int wc   = w & 3;           // 0..3  (cols: wc*64)

  // XCD 2D super-tiling: tile grid 32x32; XCD (I,J): bi in [I*16,+16), bj in [J*8,+8).
  // Block b: xcd = b&7 -> I=(b&7)>>2, J=b&3; within: wi = b>>3 (0..31):
  // bi = I*16 + (wi>>1), bj0 = J*8 + (wi&1)*4; block owns tiles (bi, bj0..bj0+3).
  const int b   = blockIdx.x;
  const int I   = (b & 7) >> 2;
  const int J   = b & 3;
  const int wi  = b >> 3;
  const int bi  = I * 16 + (wi >> 1);
  const int bj0 = J * 8 + (wi & 1) * 4;

  // staging geometry: LDS byte = row*128 + slot*16 (linear), slot = tid&7,
  // row = l*64 + (tid>>3); source pre-swizzled: kgroup = slot ^ (row&7).
  const int r64  = tid >> 3;               // 0..63
  const int kgrp = (tid & 7) ^ (r64 & 7);
  const unsigned short* Abase = Xc + (size_t)(bi * 256 + r64) * KC + kgrp * 8;

  auto STAGE = [&](int buf, int nt, int nkt) {
    const unsigned short* Asrc = Abase + nkt * 64;
    const unsigned short* Bsrc = Yc + (size_t)((bj0 + nt) * 256 + r64) * KC + kgrp * 8 + nkt * 64;
    char* Ad = (char*)&As[buf][0] + w * 1024;      // wave-uniform LDS base
    char* Bd = (char*)&Bs[buf][0] + w * 1024;
    #pragma unroll
    for (int l = 0; l < 4; ++l) {                  // 64 rows per round
      gload_lds16(Asrc + (size_t)l * 64 * KC, Ad + l * 8192);
      gload_lds16(Bsrc + (size_t)l * 64 * KC, Bd + l * 8192);
    }
  };

  STAGE(0, 0, 0);

  for (int t = 0; t < 4; ++t) {
    const int bj = bj0 + t;

    // acc init = x2[row] + y2[col]  ->  accumulator IS the distance
    f32x4 acc[8][4];
    {
      f32x4 xv[8]; float yv[4];
      #pragma unroll
      for (int mi = 0; mi < 8; ++mi)
        xv[mi] = *reinterpret_cast<const f32x4*>(x2 + bi * 256 + wr * 128 + mi * 16 + ((lane >> 4) << 2));
      #pragma unroll
      for (int ni = 0; ni < 4; ++ni)
        yv[ni] = y2[bj * 256 + wc * 64 + ni * 16 + (lane & 15)];
      #pragma unroll
      for (int mi = 0; mi < 8; ++mi)
        #pragma unroll
        for (int ni = 0; ni < 4; ++ni)
          #pragma unroll
          for (int r = 0; r < 4; ++r)
            acc[mi][ni][r] = xv[mi][r] + yv[ni];
    }

    #pragma unroll
    for (int kt = 0; kt < 4; ++kt) {
      const int step = t * 4 + kt;
      const int buf  = step & 1;

      // stage(step) landed (own loads) + all waves' stage(step) landed + all
      // waves done reading buf^1 (so next STAGE may overwrite it)
      asm volatile("s_waitcnt vmcnt(0)" ::: "memory");
      __builtin_amdgcn_s_barrier();
      __builtin_amdgcn_sched_barrier(0);

      if (step < 15) {
        const int ns = step + 1;
        STAGE(ns & 1, ns >> 2, ns & 3);            // in flight across next barrier-wait window
      }

      const char* Ab = (const char*)&As[buf][0];
      const char* Bb = (const char*)&Bs[buf][0];

      __builtin_amdgcn_s_setprio(1);
      bf16x8 bfr[4][2];
      #pragma unroll
      for (int ni = 0; ni < 4; ++ni) {
        const int col = wc * 64 + ni * 16 + (lane & 15);
        const int swz = (col & 7) << 4;
        #pragma unroll
        for (int ks = 0; ks < 2; ++ks) {
          const int ofs = (ks * 64 + ((lane >> 4) << 4)) ^ swz;
          bfr[ni][ks] = *reinterpret_cast<const bf16x8*>(Bb + col * 128 + ofs);
        }
      }
      #pragma unroll
      for (int mi = 0; mi < 8; ++mi) {
        const int rowl = wr * 128 + mi * 16 + (lane & 15);
        const int swz  = (rowl & 7) << 4;
        const bf16x8 a0 = *reinterpret_cast<const bf16x8*>(Ab + rowl * 128 + ((  0 + ((lane >> 4) << 4)) ^ swz));
        const bf16x8 a1 = *reinterpret_cast<const bf16x8*>(Ab + rowl * 128 + (( 64 + ((lane >> 4) << 4)) ^ swz));
        #pragma unroll
        for (int ni = 0; ni < 4; ++ni) {
          acc[mi][ni] = __builtin_amdgcn_mfma_f32_16x16x32_bf16(a0, bfr[ni][0], acc[mi][ni], 0, 0, 0);
          acc[mi][ni] = __builtin_amdgcn_mfma_f32_16x16x32_bf16(a1, bfr[ni][1], acc[mi][ni], 0, 0, 0);
        }
      }
      __builtin_amdgcn_s_setprio(0);
    }

    // ---- epilogue for tile t: pure min reductions (acc already = dist) ----
    float cm[4];
    #pragma unroll
    for (int ni = 0; ni < 4; ++ni) {
      float m = 3.0e38f;
      #pragma unroll
      for (int mi = 0; mi < 8; ++mi)
        #pragma unroll
        for (int r = 0; r < 4; ++r)
          m = fminf(m, acc[mi][ni][r]);
      cm[ni] = m;
    }
    {
      const bool hb0 = (lane & 16) != 0;
      float s0 = hb0 ? cm[0] : cm[2];
      float s1 = hb0 ? cm[1] : cm[3];
      float r0 = __shfl_xor(s0, 16);
      float r1 = __shfl_xor(s1, 16);
      float t0 = fminf(hb0 ? cm[2] : cm[0], r0);
      float t1 = fminf(hb0 ? cm[3] : cm[1], r1);
      const bool hb1 = (lane & 32) != 0;
      float s  = hb1 ? t0 : t1;
      float rr = __shfl_xor(s, 32);
      float cfin = fminf(hb1 ? t1 : t0, rr);
      const int ni = (hb0 ? 2 : 0) + (hb1 ? 1 : 0);    // bitrev2(lane>>4)
      colminLDS[wr * 256 + wc * 64 + ni * 16 + (lane & 15)] = cfin;
    }

    float rm[32];
    #pragma unroll
    for (int mi = 0; mi < 8; ++mi)
      #pragma unroll
      for (int r = 0; r < 4; ++r)
        rm[mi * 4 + r] = fminf(fminf(acc[mi][0][r], acc[mi][1][r]),
                               fminf(acc[mi][2][r], acc[mi][3][r]));
    #pragma unroll
    for (int b2 = 0; b2 < 4; ++b2) {
      const int  half = 16 >> b2;
      const bool up   = (lane >> b2) & 1;
      #pragma unroll
      for (int i = 0; i < half; ++i) {
        float snd = up ? rm[i] : rm[i + half];
        float rcv = __shfl_xor(snd, 1 << b2);
        rm[i] = fminf(up ? rm[i + half] : rm[i], rcv);
      }
    }
    {
      // surviving rm[e], e in {0,1}: idx = l0<<4 | l1<<3 | l2<<2 | l3<<1 | e
      const int base = ((lane & 1) << 4) | ((lane & 2) << 2) | (lane & 4) | ((lane & 8) >> 2);
      #pragma unroll
      for (int e = 0; e < 2; ++e) {
        const int idx = base | e;
        const int row_local = wr * 128 + (idx >> 2) * 16 + ((lane >> 4) << 2) + (idx & 3);
        rowminLDS[wc * 256 + row_local] = rm[e];
      }
    }
    __syncthreads();

    // combine waves, clamp at 0 (commutes with min), one atomic per row/col
    if (tid < 256) {
      float c = fminf(colminLDS[tid], colminLDS[256 + tid]);
      atomicMin(&miny[bj * 256 + tid], __float_as_uint(fmaxf(c, 0.f)));
    } else {
      const int r = tid - 256;
      float v = fminf(fminf(rowminLDS[r], rowminLDS[256 + r]),
                      fminf(rowminLDS[512 + r], rowminLDS[768 + r]));
      atomicMin(&minx[bi * 256 + r], __float_as_uint(fmaxf(v, 0.f)));
    }
  }

  // ---- fused finalize: last block sums the min arrays ----
  __syncthreads();   // all this block's atomics issued & drained (vmcnt 0)
  if (tid == 0) {
    __threadfence();
    unsigned int old = __hip_atomic_fetch_add(cnt, 1u, __ATOMIC_ACQ_REL, __HIP_MEMORY_SCOPE_AGENT);
    lastFlag = (old == 255u) ? 1u : 0u;
  }
  __syncthreads();
  if (lastFlag) {
    float s = 0.f;
    for (int i = tid; i < NPTS; i += 512) {
      s += __uint_as_float(__hip_atomic_load(&minx[i], __ATOMIC_RELAXED, __HIP_MEMORY_SCOPE_AGENT));
      s += __uint_as_float(__hip_atomic_load(&miny[i], __ATOMIC_RELAXED, __HIP_MEMORY_SCOPE_AGENT));
    }
    #pragma unroll
    for (int m = 32; m >= 1; m >>= 1) s += __shfl_xor(s, m);
    if (lane == 0) redLDS[w] = s;
    __syncthreads();
    if (tid == 0) {
      float tsum = 0.f;
      #pragma unroll
      for (int i = 0; i < 8; ++i) tsum += redLDS[i];
      out[0] = tsum * (1.0f / (float)NPTS);
    }
  }
}

// ---------------------------------------------------------------- launch ----
extern "C" void kernel_launch(void* const* d_in, const int* in_sizes, int n_in,
                              void* d_out, int out_size, void* d_ws, size_t ws_size,
                              hipStream_t stream) {
  (void)in_sizes; (void)n_in; (void)out_size; (void)ws_size;
  const float* x = (const float*)d_in[0];
  const float* y = (const float*)d_in[1];
  char* ws = (char*)d_ws;

  // ws layout: Xc 4MB | Yc 4MB | x2 32KB | y2 32KB | minx 32KB | miny 32KB | cnt
  unsigned short* Xc  = (unsigned short*)(ws);
  unsigned short* Yc  = (unsigned short*)(ws + 4194304);
  float*          x2  = (float*)(ws + 8388608);
  float*          y2  = (float*)(ws + 8421376);
  unsigned int*   mnx = (unsigned int*)(ws + 8454144);
  unsigned int*   mny = (unsigned int*)(ws + 8486912);
  unsigned int*   cnt = (unsigned int*)(ws + 8519680);
  float*          out = (float*)d_out;

  prep_kernel<<<2048, 256, 0, stream>>>(x, y, Xc, Yc, x2, y2, mnx, mny, cnt);
  chamfer_gemm<<<256, 512, 0, stream>>>(Xc, Yc, x2, y2, mnx, mny, cnt, out);
}